// Round 10
// baseline (236.281 us; speedup 1.0000x reference)
//
#include <hip/hip_runtime.h>
#include <hip/hip_bf16.h>

#define SPAT 32768   // 32*32*32
#define BATCH 2
#define GN_EPS 1e-5f
#define CPAD 224     // cv4 padded output channels (216 -> 224)

typedef __attribute__((ext_vector_type(8))) short bf16x8;
typedef __attribute__((ext_vector_type(4))) float f32x4;

__device__ __forceinline__ short f2bf(float f) {
    __hip_bfloat16 h = __float2bfloat16(f);
    return *reinterpret_cast<short*>(&h);
}

// ============ MFMA pointwise conv ============
// out[o][s] = act(affine(sum_c w[o][c] * in[c][s]))  via 16x16x32 bf16 MFMA.
// M=spatial (128/block), N=o, K=c. Block 256 (4 waves x 2 m-tiles).
// A loaded DIRECTLY global->VGPR (no LDS transpose); weights staged bf16 in
// LDS with +8-short row pad (b128 reads land 2-way = free).
// A[m=lane&15][k=quad*8+j], B[k=quad*8+j][n=lane&15], D[m=quad*4+r][n=lane&15].
template <int CIN, int COUT, int COUT_REAL, bool RELU, bool AFF, bool STATS, bool RES>
__global__ __launch_bounds__(256) void k_mfma_pw(
    const float* __restrict__ in, const float* __restrict__ w,
    const float* __restrict__ sc, const float* __restrict__ bi,
    const float* __restrict__ yres,
    float* __restrict__ out, float* __restrict__ partial)
{
    constexpr int LT = CIN + 8;          // LDS row stride (shorts)
    constexpr int KS = CIN / 32;
    constexpr int NT = COUT / 16;
    __shared__ short wt[COUT * LT];      // weights [o][c] bf16
    int tid = threadIdx.x;
    int b = blockIdx.z;
    int s0 = blockIdx.x * 128;

    // ---- stage weights (contiguous short writes: conflict-free) ----
#pragma unroll
    for (int it = 0; it < COUT * CIN / 256; ++it) {
        int j = tid + it * 256;
        int o = j / CIN, c = j % CIN;
        float wv = (COUT == COUT_REAL || o < COUT_REAL) ? w[o * CIN + c] : 0.f;
        wt[o * LT + c] = f2bf(wv);
    }

    int wave = tid >> 6, lane = tid & 63, quad = lane >> 4, l15 = lane & 15;
    int wp0 = wave * 32;                 // 2 m-tiles per wave

    // ---- A-fragments: direct global loads (coalesced over l15), cvt to bf16 ----
    bf16x8 afr[2][KS];
#pragma unroll
    for (int m = 0; m < 2; ++m) {
        int p = s0 + wp0 + m * 16 + l15;
        const float* ap = in + (size_t)b * CIN * SPAT + p;
#pragma unroll
        for (int kk = 0; kk < KS; ++kk) {
            bf16x8 v;
#pragma unroll
            for (int j = 0; j < 8; ++j)
                v[j] = f2bf(ap[(size_t)(kk * 32 + quad * 8 + j) * SPAT]);
            afr[m][kk] = v;
        }
    }
    __syncthreads();

    for (int nt = 0; nt < NT; ++nt) {
        int o = nt * 16 + l15;
        bf16x8 bfr[KS];
#pragma unroll
        for (int kk = 0; kk < KS; ++kk)
            bfr[kk] = *(const bf16x8*)&wt[o * LT + kk * 32 + quad * 8];
        f32x4 acc[2] = {{0.f, 0.f, 0.f, 0.f}, {0.f, 0.f, 0.f, 0.f}};
#pragma unroll
        for (int kk = 0; kk < KS; ++kk) {
            acc[0] = __builtin_amdgcn_mfma_f32_16x16x32_bf16(afr[0][kk], bfr[kk], acc[0], 0, 0, 0);
            acc[1] = __builtin_amdgcn_mfma_f32_16x16x32_bf16(afr[1][kk], bfr[kk], acc[1], 0, 0, 0);
        }
        float scale = AFF ? sc[o] : 1.f;
        float shift = (COUT == COUT_REAL || o < COUT_REAL) ? bi[o] : 0.f;
        float psum = 0.f, pss = 0.f;
#pragma unroll
        for (int m = 0; m < 2; ++m) {
            int pos = s0 + wp0 + m * 16 + quad * 4;
            float4 r;
            r.x = acc[m][0] * scale + shift;
            r.y = acc[m][1] * scale + shift;
            r.z = acc[m][2] * scale + shift;
            r.w = acc[m][3] * scale + shift;
            if (RELU) {
                r.x = fmaxf(r.x, 0.f); r.y = fmaxf(r.y, 0.f);
                r.z = fmaxf(r.z, 0.f); r.w = fmaxf(r.w, 0.f);
            }
            if (RES) {
                float4 yv = *(const float4*)(yres + ((size_t)(b * COUT + o)) * SPAT + pos);
                r.x += yv.x; r.y += yv.y; r.z += yv.z; r.w += yv.w;
            }
            *(float4*)(out + ((size_t)b * COUT + o) * SPAT + pos) = r;
            if (STATS) {
                psum += r.x + r.y + r.z + r.w;
                pss  += r.x * r.x + r.y * r.y + r.z * r.z + r.w * r.w;
            }
        }
        if (STATS) {
            psum += __shfl_xor(psum, 16, 64); pss += __shfl_xor(pss, 16, 64);
            psum += __shfl_xor(psum, 32, 64); pss += __shfl_xor(pss, 32, 64);
            if (quad == 0) {
                int chunk = blockIdx.x * 4 + wave;         // 0..1023
                int idx = (((b * COUT + o) << 10) + chunk) * 2;
                partial[idx + 0] = psum;
                partial[idx + 1] = pss;
            }
        }
    }
}

// ============ GN stats stage 2: reduce 27 o x 1024 chunks per (b,g) ============
__global__ __launch_bounds__(256) void k_gn_stats2(
    const float* __restrict__ partial, float* __restrict__ stats)
{
    int bg = blockIdx.x;
    int b = bg >> 3, g = bg & 7;
    float sum = 0.f, ss = 0.f;
    for (int i = threadIdx.x; i < 27 * 1024; i += 256) {
        int o = g * 27 + (i >> 10);
        int ch = i & 1023;
        int idx = (((b * CPAD + o) << 10) + ch) * 2;
        sum += partial[idx + 0];
        ss  += partial[idx + 1];
    }
    __shared__ float sh[512];
    sh[threadIdx.x] = sum; sh[256 + threadIdx.x] = ss;
    __syncthreads();
    for (int off = 128; off > 0; off >>= 1) {
        if (threadIdx.x < off) {
            sh[threadIdx.x] += sh[threadIdx.x + off];
            sh[256 + threadIdx.x] += sh[256 + threadIdx.x + off];
        }
        __syncthreads();
    }
    if (threadIdx.x == 0) {
        stats[bg * 2 + 0] = sh[0];
        stats[bg * 2 + 1] = sh[256];
    }
}

// ============ depthwise 5x5x5, zero pad 2, + affine, LDS-tiled ============
__global__ __launch_bounds__(256) void k_dw5(
    const float* __restrict__ in, const float* __restrict__ w2,
    const float* __restrict__ s2, const float* __restrict__ b2,
    float* __restrict__ out)
{
    __shared__ float lds[8 * 36 * 40];
    int tid = threadIdx.x;
    int d0 = blockIdx.x * 4;
    int c = blockIdx.y, b = blockIdx.z;
    const float* ip = in + ((size_t)(b * 32 + c)) * SPAT;

    float4 z = {0, 0, 0, 0};
    for (int i = tid; i < 8 * 36 * 40 / 4; i += 256)
        ((float4*)lds)[i] = z;
    __syncthreads();
    for (int i = tid; i < 8 * 256; i += 256) {
        int p = i >> 8, rem = i & 255;
        int r = rem >> 3, c4 = (rem & 7) * 4;
        int d = d0 - 2 + p;
        if (d >= 0 && d < 32) {
            float4 v = *(const float4*)(ip + d * 1024 + r * 32 + c4);
            *(float4*)&lds[p * 1440 + (r + 2) * 40 + (c4 + 4)] = v;
        }
    }
    __syncthreads();

    float scl = s2[c], shf = b2[c];
    const float* wt = w2 + c * 125;
#pragma unroll
    for (int k = 0; k < 4; ++k) {
        int j = tid + k * 256;
        int pd = j >> 8, rem = j & 255;
        int hr = rem >> 3, w4 = (rem & 7) * 4;
        float4 acc = {0, 0, 0, 0};
#pragma unroll
        for (int kd = 0; kd < 5; ++kd) {
            const float* pl = &lds[(pd + kd) * 1440];
#pragma unroll
            for (int kh = 0; kh < 5; ++kh) {
                const float* row = pl + (hr + kh) * 40 + w4;
                float4 r0 = *(const float4*)(row);
                float4 r1 = *(const float4*)(row + 4);
                float4 r2 = *(const float4*)(row + 8);
                float win[12] = {r0.x, r0.y, r0.z, r0.w,
                                 r1.x, r1.y, r1.z, r1.w,
                                 r2.x, r2.y, r2.z, r2.w};
#pragma unroll
                for (int kw = 0; kw < 5; ++kw) {
                    float wv = wt[kd * 25 + kh * 5 + kw];
                    acc.x = fmaf(wv, win[2 + 0 + kw], acc.x);
                    acc.y = fmaf(wv, win[2 + 1 + kw], acc.y);
                    acc.z = fmaf(wv, win[2 + 2 + kw], acc.z);
                    acc.w = fmaf(wv, win[2 + 3 + kw], acc.w);
                }
            }
        }
        acc.x = acc.x * scl + shf; acc.y = acc.y * scl + shf;
        acc.z = acc.z * scl + shf; acc.w = acc.w * scl + shf;
        *(float4*)(out + ((size_t)(b * 32 + c)) * SPAT
                   + (d0 + pd) * 1024 + hr * 32 + w4) = acc;
    }
}

// ============ SKA (round-5 proven; wk stride CPAD) ============
__global__ __launch_bounds__(256) void k_ska(
    const float* __restrict__ x, const float* __restrict__ wk,
    const float* __restrict__ stats,
    const float* __restrict__ gn_g, const float* __restrict__ gn_b,
    const float* __restrict__ bn_s, const float* __restrict__ bn_b,
    float* __restrict__ y)
{
    int q = blockIdx.x * 256 + threadIdx.x;
    int s = q * 4;
    int g = blockIdx.y, b = blockIdx.z;
    int bg = b * 8 + g;
    const float N = 27.f * (float)SPAT;
    float mu  = stats[bg * 2 + 0] / N;
    float var = stats[bg * 2 + 1] / N - mu * mu;
    float inv = rsqrtf(var + GN_EPS);
    int d = s >> 10, h = (s >> 5) & 31, w0 = s & 31;
    int lane = threadIdx.x & 63;
    int xl_src = (lane & 56) | ((lane + 7) & 7);
    int xr_src = (lane & 56) | ((lane + 1) & 7);
    const float* xg = x + ((size_t)(b * 64 + g * 8)) * SPAT;
    const float* wp = wk + ((size_t)(b * CPAD + g * 27)) * SPAT + s;

    float4 acc[8];
    float4 xc[8];
#pragma unroll
    for (int c = 0; c < 8; ++c) acc[c] = {0, 0, 0, 0};

#pragma unroll
    for (int kd = 0; kd < 3; ++kd) {
        int zd = (d + kd + 31) & 31;
#pragma unroll
        for (int kh = 0; kh < 3; ++kh) {
            int zh = (h + kh + 31) & 31;
            int kbase = (kd * 3 + kh) * 3;
            float wn[3][4];
#pragma unroll
            for (int kw = 0; kw < 3; ++kw) {
                int kk = kbase + kw;
                float4 wq = *(const float4*)(wp + (size_t)kk * SPAT);
                float gg = gn_g[g * 27 + kk], gb = gn_b[g * 27 + kk];
                wn[kw][0] = (wq.x - mu) * inv * gg + gb;
                wn[kw][1] = (wq.y - mu) * inv * gg + gb;
                wn[kw][2] = (wq.z - mu) * inv * gg + gb;
                wn[kw][3] = (wq.w - mu) * inv * gg + gb;
            }
            int rowoff = zd * 1024 + zh * 32;
            bool center = (kd == 1) && (kh == 1);
#pragma unroll
            for (int c = 0; c < 8; ++c) {
                float4 m = *(const float4*)(xg + (size_t)c * SPAT + rowoff + w0);
                if (center) xc[c] = m;
                float xl = __shfl(m.w, xl_src, 64);
                float xr = __shfl(m.x, xr_src, 64);
                float win[6] = {xl, m.x, m.y, m.z, m.w, xr};
#pragma unroll
                for (int kw = 0; kw < 3; ++kw) {
                    acc[c].x = fmaf(win[0 + kw], wn[kw][0], acc[c].x);
                    acc[c].y = fmaf(win[1 + kw], wn[kw][1], acc[c].y);
                    acc[c].z = fmaf(win[2 + kw], wn[kw][2], acc[c].z);
                    acc[c].w = fmaf(win[3 + kw], wn[kw][3], acc[c].w);
                }
            }
        }
    }
#pragma unroll
    for (int c = 0; c < 8; ++c) {
        int ch = g * 8 + c;
        float bs = bn_s[ch], bb = bn_b[ch];
        float4 r;
        r.x = acc[c].x * bs + bb + xc[c].x;
        r.y = acc[c].y * bs + bb + xc[c].y;
        r.z = acc[c].z * bs + bb + xc[c].z;
        r.w = acc[c].w * bs + bb + xc[c].w;
        *(float4*)(y + ((size_t)(b * 64 + ch)) * SPAT + s) = r;
    }
}

extern "C" void kernel_launch(void* const* d_in, const int* in_sizes, int n_in,
                              void* d_out, int out_size, void* d_ws, size_t ws_size,
                              hipStream_t stream)
{
    const float* x     = (const float*)d_in[0];
    const float* w1    = (const float*)d_in[1];
    const float* s1    = (const float*)d_in[2];
    const float* b1    = (const float*)d_in[3];
    const float* w2    = (const float*)d_in[4];
    const float* s2    = (const float*)d_in[5];
    const float* b2    = (const float*)d_in[6];
    const float* w3    = (const float*)d_in[7];
    const float* s3    = (const float*)d_in[8];
    const float* b3    = (const float*)d_in[9];
    const float* w4    = (const float*)d_in[10];
    const float* b4    = (const float*)d_in[11];
    const float* gn_g  = (const float*)d_in[12];
    const float* gn_b  = (const float*)d_in[13];
    const float* bn_s  = (const float*)d_in[14];
    const float* bn_b  = (const float*)d_in[15];
    const float* pw1_w = (const float*)d_in[16];
    const float* pw1_s = (const float*)d_in[17];
    const float* pw1_b = (const float*)d_in[18];
    const float* pw2_w = (const float*)d_in[19];
    const float* pw2_s = (const float*)d_in[20];
    const float* pw2_b = (const float*)d_in[21];

    // ws: a1 | a2 | yb | wk(224 rows) | f1 | part | stats  (~134 MB)
    float* ws    = (float*)d_ws;
    float* a1    = ws;                                    // 2*32*S
    float* a2    = a1 + (size_t)BATCH * 32 * SPAT;        // 2*32*S
    float* yb    = a2 + (size_t)BATCH * 32 * SPAT;        // 2*64*S
    float* wkb   = yb + (size_t)BATCH * 64 * SPAT;        // 2*224*S
    float* f1    = wkb + (size_t)BATCH * CPAD * SPAT;     // 2*128*S
    float* part  = f1 + (size_t)BATCH * 128 * SPAT;       // 2*224*1024*2
    float* stats = part + (size_t)BATCH * CPAD * 1024 * 2;// 32

    dim3 blk(256);
    dim3 gmm(SPAT / 128, 1, BATCH);                       // 512 blocks
    // cv1 + BN + ReLU : 64 -> 32 (MFMA)
    k_mfma_pw<64, 32, 32, true, true, false, false><<<gmm, blk, 0, stream>>>(
        x, w1, s1, b1, nullptr, a1, nullptr);
    // dw 5^3 + BN
    k_dw5<<<dim3(8, 32, BATCH), blk, 0, stream>>>(a1, w2, s2, b2, a2);
    // cv3 + BN + ReLU : 32 -> 32 (MFMA)
    k_mfma_pw<32, 32, 32, true, true, false, false><<<gmm, blk, 0, stream>>>(
        a2, w3, s3, b3, nullptr, a1, nullptr);
    // cv4 + bias : 32 -> 216(pad 224) (MFMA, fused GN partials)
    k_mfma_pw<32, CPAD, 216, false, false, true, false><<<gmm, blk, 0, stream>>>(
        a1, w4, nullptr, b4, nullptr, wkb, part);
    // GN stats stage 2
    k_gn_stats2<<<dim3(16), blk, 0, stream>>>(part, stats);
    // SKA + BN + residual -> y
    k_ska<<<dim3(SPAT / 1024, 8, BATCH), blk, 0, stream>>>(
        x, wkb, stats, gn_g, gn_b, bn_s, bn_b, yb);
    // pw1 + BN + ReLU : 64 -> 128 (MFMA)
    k_mfma_pw<64, 128, 128, true, true, false, false><<<gmm, blk, 0, stream>>>(
        yb, pw1_w, pw1_s, pw1_b, nullptr, f1, nullptr);
    // pw2 + BN + residual -> out : 128 -> 64 (MFMA)
    k_mfma_pw<128, 64, 64, false, true, false, true><<<gmm, blk, 0, stream>>>(
        f1, pw2_w, pw2_s, pw2_b, yb, (float*)d_out, nullptr);
}